// Round 4
// baseline (312.973 us; speedup 1.0000x reference)
//
#include <hip/hip_runtime.h>
#include <hip/hip_bf16.h>
#include <stdint.h>

// Problem constants (reference: B=4, S=2048, D_IN=D_K=D_V=1024)
#define B_ 4
#define S_ 2048
#define D_ 1024

typedef __attribute__((ext_vector_type(8))) short short8;   // 8 bf16 = 4 VGPRs
typedef __attribute__((ext_vector_type(4))) float floatx4;  // MFMA C/D

__device__ __forceinline__ unsigned short bf16_rne(float f) {
  union { float f; uint32_t u; } c; c.f = f;
  uint32_t u = c.u;
  return (unsigned short)((u + 0x7fffu + ((u >> 16) & 1u)) >> 16);
}

__device__ __forceinline__ void gl2lds16(const void* g, void* l) {
  // async global->LDS, 16B per lane; LDS dest is wave-uniform base + lane*16
  __builtin_amdgcn_global_load_lds(
      (const __attribute__((address_space(1))) void*)g,
      (__attribute__((address_space(3))) void*)l, 16, 0, 0);
}

// ---- merged prep: casts of query/key/Wq/Wk, bias packing, value transpose ----
__global__ __launch_bounds__(256) void prep_all(
    const float* __restrict__ q, const float* __restrict__ k,
    const float* __restrict__ wq, const float* __restrict__ wk,
    const float* __restrict__ bq, const float* __restrict__ bk,
    const float* __restrict__ v,
    unsigned short* __restrict__ oq, unsigned short* __restrict__ ok,
    unsigned short* __restrict__ owq, unsigned short* __restrict__ owk,
    float* __restrict__ bias, unsigned short* __restrict__ vt) {
  __shared__ float tile[32][33];
  const int blk = blockIdx.x;
  if (blk < 18432) {
    int i = blk * 256 + threadIdx.x;
    const float* src; unsigned short* dst; int off;
    if (i < 2097152)      { src = q;  dst = oq;  off = i; }
    else if (i < 4194304) { src = k;  dst = ok;  off = i - 2097152; }
    else if (i < 4456448) { src = wq; dst = owq; off = i - 4194304; }
    else                  { src = wk; dst = owk; off = i - 4456448; }
    float4 vv = ((const float4*)src)[off];
    uint32_t p0 = (uint32_t)bf16_rne(vv.x) | ((uint32_t)bf16_rne(vv.y) << 16);
    uint32_t p1 = (uint32_t)bf16_rne(vv.z) | ((uint32_t)bf16_rne(vv.w) << 16);
    ((uint2*)dst)[off] = make_uint2(p0, p1);
  } else if (blk < 18434) {
    int j = (blk - 18432) * 256 + threadIdx.x;  // 0..511
    const float* src = (j < 256) ? bq : bk;
    ((float4*)bias)[j] = ((const float4*)src)[j & 255];
  } else {
    const int bi = blk - 18434;
    const int d0 = (bi & 31) * 32;          // D/32 = 32
    const int s0 = ((bi >> 5) & 63) * 32;   // S/32 = 64
    const int b  = bi >> 11;                // B = 4
    const int tx = threadIdx.x & 31, ty = threadIdx.x >> 5;  // (32,8)
    const float* src = v + (size_t)b * S_ * D_;
#pragma unroll
    for (int i = 0; i < 4; ++i)
      tile[ty + i * 8][tx] = src[(size_t)(s0 + ty + i * 8) * D_ + d0 + tx];
    __syncthreads();
    unsigned short* dst = vt + (size_t)b * D_ * S_;
#pragma unroll
    for (int i = 0; i < 4; ++i)
      dst[(size_t)(d0 + ty + i * 8) * S_ + s0 + tx] = bf16_rne(tile[tx][ty + i * 8]);
  }
}

// ---------------- BT-GEMM: C[m,n] = sum_k A[m,k]*B[n,k], bf16 in, fp32 accum ---------------
// Block tile BM x 128, 4 waves (2x2), wave tile (BM/2) x 64.
// TRUE double-buffer: stage k-stage it+1 into buf[p^1] BEFORE computing buf[p];
// ONE barrier per k32 iter -> vmcnt(0) drain overlaps the whole compute phase.
// XOR bank swizzle: LDS slot (row,c) holds global k-chunk c^((row>>1)&3) so a
// quarter-wave's ds_read_b128 spreads across all 32 banks (2/bank = free).
// EPI 0: bf16 = acc + bias[n]; EPI 1: f32 = acc*scale; EPI 2: bf16 = acc*scale.
template <int EPI, int BM>
__global__ __launch_bounds__(256, 2) void gemm_bt(
    const unsigned short* __restrict__ A, const unsigned short* __restrict__ Bm,
    void* __restrict__ Cv, const float* __restrict__ bias,
    int N, int K, float scale,
    long long sA, long long sB, long long sC, long long sBias) {
  constexpr int IC = BM / 32;    // A-frags per wave (m direction)
  constexpr int AST = BM / 64;   // A staging instrs per thread per k32
  __shared__ unsigned short smA[2][BM * 32];
  __shared__ unsigned short smB[2][128 * 32];

  const int z = blockIdx.z;
  const unsigned short* Ab = A + (size_t)z * sA;
  const unsigned short* Bb = Bm + (size_t)z * sB;

  const int tile_n = blockIdx.x * 128;
  const int tile_m = blockIdx.y * BM;

  const int t = threadIdx.x;
  const int w = t >> 6;        // wave 0..3
  const int l = t & 63;        // lane
  const int wr = w >> 1, wc = w & 1;  // 2x2 wave grid

  floatx4 acc[IC][4];
#pragma unroll
  for (int i = 0; i < IC; ++i)
#pragma unroll
    for (int j = 0; j < 4; ++j) acc[i][j] = (floatx4){0.f, 0.f, 0.f, 0.f};

  const int srow = l >> 2;                                  // staged quarter-row
  const int scb  = ((l & 3) ^ ((l >> 3) & 3)) * 16;         // swizzled global chunk (bytes)
  const int rm   = l & 15;                                  // fragment row within 16
  const int kcsw = ((l >> 4) ^ ((rm >> 1) & 3)) * 16;       // swizzled LDS chunk (bytes)

  for (int it = 0; it <= K >> 5; ++it) {
    // ---- stage k32 stage `it` into buf[it&1] (skipped once past the end) ----
    if (it < (K >> 5)) {
      const int p = it & 1;
      const int kb = it << 6;  // byte offset along k (32 elems * 2B)
#pragma unroll
      for (int i = 0; i < AST; ++i) {
        const int r = (i * 4 + w) * 16 + srow;
        gl2lds16((const char*)Ab + (size_t)(tile_m + r) * K * 2 + kb + scb,
                 (char*)smA[p] + (i * 4 + w) * 1024);
      }
#pragma unroll
      for (int i = 0; i < 2; ++i) {
        const int r = (i * 4 + w) * 16 + srow;
        gl2lds16((const char*)Bb + (size_t)(tile_n + r) * K * 2 + kb + scb,
                 (char*)smB[p] + (i * 4 + w) * 1024);
      }
    }
    // ---- compute k32 stage `it-1` from buf[(it-1)&1] (skipped first iter) ----
    if (it > 0) {
      const int p = (it - 1) & 1;
      short8 bfr[4];
#pragma unroll
      for (int j = 0; j < 4; ++j)
        bfr[j] = *(const short8*)((const char*)smB[p] + (wc * 64 + j * 16 + rm) * 64 + kcsw);
#pragma unroll
      for (int i = 0; i < IC; ++i) {
        const short8 af = *(const short8*)((const char*)smA[p] +
                                           (wr * (BM / 2) + i * 16 + rm) * 64 + kcsw);
#pragma unroll
        for (int j = 0; j < 4; ++j)
          acc[i][j] = __builtin_amdgcn_mfma_f32_16x16x32_bf16(af, bfr[j], acc[i][j], 0, 0, 0);
      }
    }
    // one barrier per iter: proves stage `it` landed (vmcnt) AND all reads of
    // buf[(it-1)&1] finished (lgkm) before it is re-staged at iter it+1.
    __syncthreads();
  }

  // Epilogue. C/D layout: col = lane&15, row = (lane>>4)*4 + reg  [m89/m91-verified]
#pragma unroll
  for (int i = 0; i < IC; ++i) {
#pragma unroll
    for (int j = 0; j < 4; ++j) {
      const int n = tile_n + wc * 64 + j * 16 + rm;
      const int m0 = tile_m + wr * (BM / 2) + i * 16 + (l >> 4) * 4;
      if (EPI == 0) {
        const float bv = bias[(size_t)z * sBias + n];
        unsigned short* C = (unsigned short*)Cv + (size_t)z * sC;
#pragma unroll
        for (int r = 0; r < 4; ++r)
          C[(size_t)(m0 + r) * N + n] = bf16_rne(acc[i][j][r] + bv);
      } else if (EPI == 1) {
        float* C = (float*)Cv + (size_t)z * sC;
#pragma unroll
        for (int r = 0; r < 4; ++r)
          C[(size_t)(m0 + r) * N + n] = acc[i][j][r] * scale;
      } else {
        unsigned short* C = (unsigned short*)Cv + (size_t)z * sC;
#pragma unroll
        for (int r = 0; r < 4; ++r)
          C[(size_t)(m0 + r) * N + n] = bf16_rne(acc[i][j][r] * scale);
      }
    }
  }
}

// ---------------- row softmax: bf16 logits [rows,2048] -> bf16 attn ----------------
__global__ __launch_bounds__(256) void softmax_bf16(
    const unsigned short* __restrict__ logits, unsigned short* __restrict__ attn) {
  const int row = blockIdx.x;
  const int t = threadIdx.x;
  uint4 raw = *(const uint4*)(logits + (size_t)row * S_ + t * 8);
  float x[8];
  const uint32_t ru[4] = {raw.x, raw.y, raw.z, raw.w};
#pragma unroll
  for (int i = 0; i < 4; ++i) {
    union { uint32_t u; float f; } lo, hi;
    lo.u = ru[i] << 16;
    hi.u = ru[i] & 0xffff0000u;
    x[2 * i] = lo.f;
    x[2 * i + 1] = hi.f;
  }
  float m = x[0];
#pragma unroll
  for (int i = 1; i < 8; ++i) m = fmaxf(m, x[i]);
#pragma unroll
  for (int off = 32; off > 0; off >>= 1) m = fmaxf(m, __shfl_xor(m, off));
  __shared__ float sm4[4], ss4[4];
  const int wv = t >> 6, ln = t & 63;
  if (ln == 0) sm4[wv] = m;
  __syncthreads();
  m = fmaxf(fmaxf(sm4[0], sm4[1]), fmaxf(sm4[2], sm4[3]));
  float s = 0.f;
  const float LOG2E = 1.44269504088896340736f;
#pragma unroll
  for (int i = 0; i < 8; ++i) {
    x[i] = exp2f((x[i] - m) * LOG2E);
    s += x[i];
  }
#pragma unroll
  for (int off = 32; off > 0; off >>= 1) s += __shfl_xor(s, off);
  if (ln == 0) ss4[wv] = s;
  __syncthreads();
  s = ss4[0] + ss4[1] + ss4[2] + ss4[3];
  const float inv = 1.0f / s;
  uint32_t p[4];
#pragma unroll
  for (int i = 0; i < 4; ++i)
    p[i] = (uint32_t)bf16_rne(x[2 * i] * inv) |
           ((uint32_t)bf16_rne(x[2 * i + 1] * inv) << 16);
  *(uint4*)(attn + (size_t)row * S_ + t * 8) = make_uint4(p[0], p[1], p[2], p[3]);
}

extern "C" void kernel_launch(void* const* d_in, const int* in_sizes, int n_in,
                              void* d_out, int out_size, void* d_ws, size_t ws_size,
                              hipStream_t stream) {
  (void)in_sizes; (void)n_in; (void)out_size; (void)ws_size;
  const float* query  = (const float*)d_in[0];
  const float* key_in = (const float*)d_in[1];
  const float* value  = (const float*)d_in[2];
  const float* Wq     = (const float*)d_in[3];
  const float* bq     = (const float*)d_in[4];
  const float* Wk     = (const float*)d_in[5];
  const float* bk     = (const float*)d_in[6];
  // d_in[7]=Wv, d_in[8]=bv: unused by the reference math (original model quirk).
  float* out = (float*)d_out;

  // Workspace layout (149 MiB used; every byte written before read each call)
  char* ws = (char*)d_ws;
  const size_t MiB = 1024 * 1024;
  unsigned short* Xq  = (unsigned short*)(ws);              // 16 MiB  query bf16
  unsigned short* Xk  = (unsigned short*)(ws + 16 * MiB);   // 16 MiB  key_in bf16 (contiguous after Xq)
  unsigned short* Wqb = (unsigned short*)(ws + 32 * MiB);   //  2 MiB  Wq bf16
  unsigned short* Wkb = (unsigned short*)(ws + 34 * MiB);   //  2 MiB  Wk bf16 (contiguous after Wqb)
  float*          Bias= (float*)(ws + 36 * MiB);            //  8 KiB  [bq | bk] packed
  unsigned short* Vt  = (unsigned short*)(ws + 37 * MiB);   // 16 MiB  value^T bf16 [B,D,S]
  unsigned short* Qp  = (unsigned short*)(ws + 53 * MiB);   // 16 MiB  Q bf16
  unsigned short* Kp  = (unsigned short*)(ws + 69 * MiB);   // 16 MiB  K bf16 (contiguous after Qp)
  unsigned short* Lg  = (unsigned short*)(ws + 85 * MiB);   // 32 MiB  logits bf16
  unsigned short* At  = (unsigned short*)(ws + 117 * MiB);  // 32 MiB  attn bf16

  // 1) all casts + bias pack + value transpose in one dispatch
  prep_all<<<26626, 256, 0, stream>>>(query, key_in, Wq, Wk, bq, bk, value,
                                      Xq, Xk, Wqb, Wkb, Bias, Vt);

  // 2) Q & K projections fused via z (BM=256: M=8192 -> 32 m-tiles, grid 512)
  gemm_bt<0, 256><<<dim3(D_ / 128, B_ * S_ / 256, 2), 256, 0, stream>>>(
      Xq, Wqb, Qp, Bias, D_, D_, 0.f,
      (long long)B_ * S_ * D_, (long long)D_ * D_, (long long)B_ * S_ * D_, D_);

  // 3) logits = Q@K^T * D^-0.5 per batch -> bf16 (BM=256: grid 16x8x4 = 512)
  gemm_bt<2, 256><<<dim3(S_ / 128, S_ / 256, B_), 256, 0, stream>>>(
      Qp, Kp, Lg, nullptr, S_, D_, 0.03125f,
      (long long)S_ * D_, (long long)S_ * D_, (long long)S_ * S_, 0);

  // 4) attn = softmax(logits) rowwise -> bf16
  softmax_bf16<<<B_ * S_, 256, 0, stream>>>(Lg, At);

  // 5) out = attn @ value == BT-GEMM vs Vt (BM=128 keeps grid 512 = 2 blocks/CU)
  gemm_bt<1, 128><<<dim3(D_ / 128, S_ / 128, B_), 256, 0, stream>>>(
      At, Vt, out, nullptr, D_, S_, 1.0f,
      (long long)S_ * S_, (long long)D_ * S_, (long long)S_ * D_, 0);
}

// Round 5
// 286.021 us; speedup vs baseline: 1.0942x; 1.0942x over previous
//
#include <hip/hip_runtime.h>
#include <hip/hip_bf16.h>
#include <stdint.h>

// Problem constants (reference: B=4, S=2048, D_IN=D_K=D_V=1024)
#define B_ 4
#define S_ 2048
#define D_ 1024

typedef __attribute__((ext_vector_type(8))) short short8;   // 8 bf16 = 4 VGPRs
typedef __attribute__((ext_vector_type(4))) float floatx4;  // MFMA C/D

__device__ __forceinline__ unsigned short bf16_rne(float f) {
  union { float f; uint32_t u; } c; c.f = f;
  uint32_t u = c.u;
  return (unsigned short)((u + 0x7fffu + ((u >> 16) & 1u)) >> 16);
}

__device__ __forceinline__ void gl2lds16(const void* g, void* l) {
  // async global->LDS, 16B per lane; LDS dest is wave-uniform base + lane*16
  __builtin_amdgcn_global_load_lds(
      (const __attribute__((address_space(1))) void*)g,
      (__attribute__((address_space(3))) void*)l, 16, 0, 0);
}

// ---- merged prep: casts of query/key/Wq/Wk, bias packing, value transpose ----
__global__ __launch_bounds__(256) void prep_all(
    const float* __restrict__ q, const float* __restrict__ k,
    const float* __restrict__ wq, const float* __restrict__ wk,
    const float* __restrict__ bq, const float* __restrict__ bk,
    const float* __restrict__ v,
    unsigned short* __restrict__ oq, unsigned short* __restrict__ ok,
    unsigned short* __restrict__ owq, unsigned short* __restrict__ owk,
    float* __restrict__ bias, unsigned short* __restrict__ vt) {
  __shared__ float tile[32][33];
  const int blk = blockIdx.x;
  if (blk < 18432) {
    int i = blk * 256 + threadIdx.x;
    const float* src; unsigned short* dst; int off;
    if (i < 2097152)      { src = q;  dst = oq;  off = i; }
    else if (i < 4194304) { src = k;  dst = ok;  off = i - 2097152; }
    else if (i < 4456448) { src = wq; dst = owq; off = i - 4194304; }
    else                  { src = wk; dst = owk; off = i - 4456448; }
    float4 vv = ((const float4*)src)[off];
    uint32_t p0 = (uint32_t)bf16_rne(vv.x) | ((uint32_t)bf16_rne(vv.y) << 16);
    uint32_t p1 = (uint32_t)bf16_rne(vv.z) | ((uint32_t)bf16_rne(vv.w) << 16);
    ((uint2*)dst)[off] = make_uint2(p0, p1);
  } else if (blk < 18434) {
    int j = (blk - 18432) * 256 + threadIdx.x;  // 0..511
    const float* src = (j < 256) ? bq : bk;
    ((float4*)bias)[j] = ((const float4*)src)[j & 255];
  } else {
    const int bi = blk - 18434;
    const int d0 = (bi & 31) * 32;          // D/32 = 32
    const int s0 = ((bi >> 5) & 63) * 32;   // S/32 = 64
    const int b  = bi >> 11;                // B = 4
    const int tx = threadIdx.x & 31, ty = threadIdx.x >> 5;  // (32,8)
    const float* src = v + (size_t)b * S_ * D_;
#pragma unroll
    for (int i = 0; i < 4; ++i)
      tile[ty + i * 8][tx] = src[(size_t)(s0 + ty + i * 8) * D_ + d0 + tx];
    __syncthreads();
    unsigned short* dst = vt + (size_t)b * D_ * S_;
#pragma unroll
    for (int i = 0; i < 4; ++i)
      dst[(size_t)(d0 + ty + i * 8) * S_ + s0 + tx] = bf16_rne(tile[tx][ty + i * 8]);
  }
}

// ---------------- BT-GEMM: C[m,n] = sum_k A[m,k]*B[n,k], bf16 in, fp32 accum ---------------
// Block tile BM x 128, 4 waves (2x2), wave tile (BM/2) x 64. TWO BK=32 stages
// per barrier pair (round-3 structure -- fastest measured). XOR bank swizzle
// (round-4, zero conflicts): LDS slot (row,c) holds global k-chunk c^((row>>1)&3).
// XCD-aware block remap: lin%8 is the HW XCD (round-robin); give each XCD a
// CONTIGUOUS chunk of the x-fastest tile ordering so its 4MB L2 sees a compact
// ~6-8MB working set instead of the whole 32-48MB (cuts L2-fill duplication).
// EPI 0: bf16 = acc + bias[n]; EPI 1: f32 = acc*scale; EPI 2: bf16 = acc*scale.
template <int EPI, int BM>
__global__ __launch_bounds__(256, BM == 128 ? 3 : 2) void gemm_bt(
    const unsigned short* __restrict__ A, const unsigned short* __restrict__ Bm,
    void* __restrict__ Cv, const float* __restrict__ bias,
    int N, int K, float scale,
    long long sA, long long sB, long long sC, long long sBias) {
  constexpr int IC = BM / 32;    // A-frags per wave (m direction)
  constexpr int AST = BM / 64;   // A staging instrs per thread per k32
  __shared__ unsigned short smA[2][BM * 32];
  __shared__ unsigned short smB[2][128 * 32];

  // ---- XCD-aware remap (grid total divisible by 8 for all our launches) ----
  const int gx = gridDim.x, gy = gridDim.y;
  const int lin = blockIdx.x + gx * (blockIdx.y + gy * blockIdx.z);
  const int total = gx * gy * gridDim.z;
  const int g = (lin & 7) * (total >> 3) + (lin >> 3);
  const int z = g / (gx * gy);
  const int rem = g - z * (gx * gy);
  const int by = rem / gx;
  const int bx = rem - by * gx;

  const unsigned short* Ab = A + (size_t)z * sA;
  const unsigned short* Bb = Bm + (size_t)z * sB;

  const int tile_n = bx * 128;
  const int tile_m = by * BM;

  const int t = threadIdx.x;
  const int w = t >> 6;        // wave 0..3
  const int l = t & 63;        // lane
  const int wr = w >> 1, wc = w & 1;  // 2x2 wave grid

  floatx4 acc[IC][4];
#pragma unroll
  for (int i = 0; i < IC; ++i)
#pragma unroll
    for (int j = 0; j < 4; ++j) acc[i][j] = (floatx4){0.f, 0.f, 0.f, 0.f};

  const int srow = l >> 2;                                  // staged quarter-row
  const int scb  = ((l & 3) ^ ((l >> 3) & 3)) * 16;         // swizzled global chunk (bytes)
  const int rm   = l & 15;                                  // fragment row within 16
  const int kcsw = ((l >> 4) ^ ((rm >> 1) & 3)) * 16;       // swizzled LDS chunk (bytes)

  for (int kt = 0; kt < K; kt += 64) {
#pragma unroll
    for (int h = 0; h < 2; ++h) {
#pragma unroll
      for (int i = 0; i < AST; ++i) {
        const int r = (i * 4 + w) * 16 + srow;
        gl2lds16((const char*)Ab + (size_t)(tile_m + r) * K * 2 + (kt + h * 32) * 2 + scb,
                 (char*)smA[h] + (i * 4 + w) * 1024);
      }
#pragma unroll
      for (int i = 0; i < 2; ++i) {
        const int r = (i * 4 + w) * 16 + srow;
        gl2lds16((const char*)Bb + (size_t)(tile_n + r) * K * 2 + (kt + h * 32) * 2 + scb,
                 (char*)smB[h] + (i * 4 + w) * 1024);
      }
    }
    __syncthreads();  // drains vmcnt -> both staged tiles visible

#pragma unroll
    for (int h = 0; h < 2; ++h) {
      short8 bfr[4];
#pragma unroll
      for (int j = 0; j < 4; ++j)
        bfr[j] = *(const short8*)((const char*)smB[h] + (wc * 64 + j * 16 + rm) * 64 + kcsw);
#pragma unroll
      for (int i = 0; i < IC; ++i) {
        const short8 af = *(const short8*)((const char*)smA[h] +
                                           (wr * (BM / 2) + i * 16 + rm) * 64 + kcsw);
#pragma unroll
        for (int j = 0; j < 4; ++j)
          acc[i][j] = __builtin_amdgcn_mfma_f32_16x16x32_bf16(af, bfr[j], acc[i][j], 0, 0, 0);
      }
    }
    __syncthreads();  // protect LDS before next stage
  }

  // Epilogue. C/D layout: col = lane&15, row = (lane>>4)*4 + reg  [m89/m91-verified]
#pragma unroll
  for (int i = 0; i < IC; ++i) {
#pragma unroll
    for (int j = 0; j < 4; ++j) {
      const int n = tile_n + wc * 64 + j * 16 + rm;
      const int m0 = tile_m + wr * (BM / 2) + i * 16 + (l >> 4) * 4;
      if (EPI == 0) {
        const float bv = bias[(size_t)z * sBias + n];
        unsigned short* C = (unsigned short*)Cv + (size_t)z * sC;
#pragma unroll
        for (int r = 0; r < 4; ++r)
          C[(size_t)(m0 + r) * N + n] = bf16_rne(acc[i][j][r] + bv);
      } else if (EPI == 1) {
        float* C = (float*)Cv + (size_t)z * sC;
#pragma unroll
        for (int r = 0; r < 4; ++r)
          C[(size_t)(m0 + r) * N + n] = acc[i][j][r] * scale;
      } else {
        unsigned short* C = (unsigned short*)Cv + (size_t)z * sC;
#pragma unroll
        for (int r = 0; r < 4; ++r)
          C[(size_t)(m0 + r) * N + n] = bf16_rne(acc[i][j][r] * scale);
      }
    }
  }
}

// ---------------- row softmax: bf16 logits [rows,2048] -> bf16 attn ----------------
__global__ __launch_bounds__(256) void softmax_bf16(
    const unsigned short* __restrict__ logits, unsigned short* __restrict__ attn) {
  const int row = blockIdx.x;
  const int t = threadIdx.x;
  uint4 raw = *(const uint4*)(logits + (size_t)row * S_ + t * 8);
  float x[8];
  const uint32_t ru[4] = {raw.x, raw.y, raw.z, raw.w};
#pragma unroll
  for (int i = 0; i < 4; ++i) {
    union { uint32_t u; float f; } lo, hi;
    lo.u = ru[i] << 16;
    hi.u = ru[i] & 0xffff0000u;
    x[2 * i] = lo.f;
    x[2 * i + 1] = hi.f;
  }
  float m = x[0];
#pragma unroll
  for (int i = 1; i < 8; ++i) m = fmaxf(m, x[i]);
#pragma unroll
  for (int off = 32; off > 0; off >>= 1) m = fmaxf(m, __shfl_xor(m, off));
  __shared__ float sm4[4], ss4[4];
  const int wv = t >> 6, ln = t & 63;
  if (ln == 0) sm4[wv] = m;
  __syncthreads();
  m = fmaxf(fmaxf(sm4[0], sm4[1]), fmaxf(sm4[2], sm4[3]));
  float s = 0.f;
  const float LOG2E = 1.44269504088896340736f;
#pragma unroll
  for (int i = 0; i < 8; ++i) {
    x[i] = exp2f((x[i] - m) * LOG2E);
    s += x[i];
  }
#pragma unroll
  for (int off = 32; off > 0; off >>= 1) s += __shfl_xor(s, off);
  if (ln == 0) ss4[wv] = s;
  __syncthreads();
  s = ss4[0] + ss4[1] + ss4[2] + ss4[3];
  const float inv = 1.0f / s;
  uint32_t p[4];
#pragma unroll
  for (int i = 0; i < 4; ++i)
    p[i] = (uint32_t)bf16_rne(x[2 * i] * inv) |
           ((uint32_t)bf16_rne(x[2 * i + 1] * inv) << 16);
  *(uint4*)(attn + (size_t)row * S_ + t * 8) = make_uint4(p[0], p[1], p[2], p[3]);
}

extern "C" void kernel_launch(void* const* d_in, const int* in_sizes, int n_in,
                              void* d_out, int out_size, void* d_ws, size_t ws_size,
                              hipStream_t stream) {
  (void)in_sizes; (void)n_in; (void)out_size; (void)ws_size;
  const float* query  = (const float*)d_in[0];
  const float* key_in = (const float*)d_in[1];
  const float* value  = (const float*)d_in[2];
  const float* Wq     = (const float*)d_in[3];
  const float* bq     = (const float*)d_in[4];
  const float* Wk     = (const float*)d_in[5];
  const float* bk     = (const float*)d_in[6];
  // d_in[7]=Wv, d_in[8]=bv: unused by the reference math (original model quirk).
  float* out = (float*)d_out;

  // Workspace layout (149 MiB used; every byte written before read each call)
  char* ws = (char*)d_ws;
  const size_t MiB = 1024 * 1024;
  unsigned short* Xq  = (unsigned short*)(ws);              // 16 MiB  query bf16
  unsigned short* Xk  = (unsigned short*)(ws + 16 * MiB);   // 16 MiB  key_in bf16 (contiguous after Xq)
  unsigned short* Wqb = (unsigned short*)(ws + 32 * MiB);   //  2 MiB  Wq bf16
  unsigned short* Wkb = (unsigned short*)(ws + 34 * MiB);   //  2 MiB  Wk bf16 (contiguous after Wqb)
  float*          Bias= (float*)(ws + 36 * MiB);            //  8 KiB  [bq | bk] packed
  unsigned short* Vt  = (unsigned short*)(ws + 37 * MiB);   // 16 MiB  value^T bf16 [B,D,S]
  unsigned short* Qp  = (unsigned short*)(ws + 53 * MiB);   // 16 MiB  Q bf16
  unsigned short* Kp  = (unsigned short*)(ws + 69 * MiB);   // 16 MiB  K bf16 (contiguous after Qp)
  unsigned short* Lg  = (unsigned short*)(ws + 85 * MiB);   // 32 MiB  logits bf16
  unsigned short* At  = (unsigned short*)(ws + 117 * MiB);  // 32 MiB  attn bf16

  // 1) all casts + bias pack + value transpose in one dispatch
  prep_all<<<26626, 256, 0, stream>>>(query, key_in, Wq, Wk, bq, bk, value,
                                      Xq, Xk, Wqb, Wkb, Bias, Vt);

  // 2) Q & K projections fused via z (BM=256: grid 8x32x2 = 512)
  gemm_bt<0, 256><<<dim3(D_ / 128, B_ * S_ / 256, 2), 256, 0, stream>>>(
      Xq, Wqb, Qp, Bias, D_, D_, 0.f,
      (long long)B_ * S_ * D_, (long long)D_ * D_, (long long)B_ * S_ * D_, D_);

  // 3) logits = Q@K^T * D^-0.5 per batch -> bf16 (BM=256: grid 16x8x4 = 512)
  gemm_bt<2, 256><<<dim3(S_ / 128, S_ / 256, B_), 256, 0, stream>>>(
      Qp, Kp, Lg, nullptr, S_, D_, 0.03125f,
      (long long)S_ * D_, (long long)S_ * D_, (long long)S_ * S_, 0);

  // 4) attn = softmax(logits) rowwise -> bf16
  softmax_bf16<<<B_ * S_, 256, 0, stream>>>(Lg, At);

  // 5) out = attn @ value == BT-GEMM vs Vt (BM=128: grid 8x16x4 = 512)
  gemm_bt<1, 128><<<dim3(D_ / 128, S_ / 128, B_), 256, 0, stream>>>(
      At, Vt, out, nullptr, D_, S_, 1.0f,
      (long long)S_ * S_, (long long)D_ * S_, (long long)S_ * D_, 0);
}